// Round 1
// baseline (2142.355 us; speedup 1.0000x reference)
//
#include <hip/hip_runtime.h>

#define NEG 0.2f

__device__ __forceinline__ float sigmoidf_(float v){ return 1.f/(1.f+__expf(-v)); }

// ---------------- encoder: h = relu([x,pos,temb[nt]] @ W1 + b1) @ W2 + b2 ----------------
__global__ __launch_bounds__(256) void enc_kernel(
    const float* __restrict__ x, const float* __restrict__ pos,
    const int* __restrict__ ntype, const float* __restrict__ temb,
    const float* __restrict__ W1, const float* __restrict__ b1,
    const float* __restrict__ W2, const float* __restrict__ b2,
    float* __restrict__ hout, int N)
{
  __shared__ float sW1[18*64];
  __shared__ float sW2[64*64];
  __shared__ float sb1[64], sb2[64];
  for (int i=threadIdx.x; i<18*64; i+=256) sW1[i]=W1[i];
  for (int i=threadIdx.x; i<64*64; i+=256) sW2[i]=W2[i];
  if (threadIdx.x<64){ sb1[threadIdx.x]=b1[threadIdx.x]; sb2[threadIdx.x]=b2[threadIdx.x]; }
  __syncthreads();
  int lane = threadIdx.x & 63;
  int n0 = (blockIdx.x*4 + (threadIdx.x>>6))*4;
  if (n0 >= N) return;
  float f[4];
  #pragma unroll
  for (int m=0;m<4;m++){
    int n=n0+m; f[m]=0.f;
    if (n<N){
      if (lane<7)       f[m]=x[(size_t)n*7+lane];
      else if (lane<10) f[m]=pos[(size_t)n*3+lane-7];
      else if (lane<18) f[m]=temb[ntype[n]*8+lane-10];
    }
  }
  float t[4];
  #pragma unroll
  for (int m=0;m<4;m++) t[m]=sb1[lane];
  for (int k=0;k<18;k++){
    float w=sW1[k*64+lane];
    #pragma unroll
    for (int m=0;m<4;m++) t[m] += __shfl(f[m],k)*w;
  }
  #pragma unroll
  for (int m=0;m<4;m++) t[m]=fmaxf(t[m],0.f);
  float o[4];
  #pragma unroll
  for (int m=0;m<4;m++) o[m]=sb2[lane];
  for (int k=0;k<64;k++){
    float w=sW2[k*64+lane];
    #pragma unroll
    for (int m=0;m<4;m++) o[m] += __shfl(t[m],k)*w;
  }
  #pragma unroll
  for (int m=0;m<4;m++){ int n=n0+m; if (n<N) hout[(size_t)n*64+lane]=o[m]; }
}

// ---------------- deg + loop_attr sums ----------------
__global__ void deg_kernel(const int* __restrict__ ei, const float* __restrict__ eattr,
                           int* __restrict__ deg, float* __restrict__ lsum, int E)
{
  int e = blockIdx.x*256 + threadIdx.x;
  if (e>=E) return;
  int dst = ei[E+e];
  atomicAdd(deg+dst, 1);
  #pragma unroll
  for (int k=0;k<6;k++) atomicAdd(lsum + (size_t)dst*6 + k, eattr[(size_t)e*6+k]);
}

__global__ void lnorm_kernel(const int* __restrict__ deg, float* __restrict__ lsum, int N)
{
  int n = blockIdx.x*256 + threadIdx.x;
  if (n>=N) return;
  float d = fmaxf((float)deg[n], 1.f);
  #pragma unroll
  for (int k=0;k<6;k++) lsum[(size_t)n*6+k] /= d;
}

// ---------------- exclusive scan of (deg+1) -> offs[N+1], single block ----------------
__global__ __launch_bounds__(1024) void scan_kernel(const int* __restrict__ deg, int* __restrict__ offs, int N)
{
  __shared__ int wsum[16];
  __shared__ int woff[16];
  __shared__ int carry_s;
  int lane = threadIdx.x & 63;
  int w = threadIdx.x >> 6;
  if (threadIdx.x == 0) carry_s = 0;
  __syncthreads();
  for (int base = 0; base < N; base += 1024){
    int i = base + (int)threadIdx.x;
    int v = (i < N) ? (deg[i] + 1) : 0;
    int inc = v;
    #pragma unroll
    for (int d = 1; d < 64; d <<= 1){
      int t = __shfl_up(inc, d);
      if (lane >= d) inc += t;
    }
    if (lane == 63) wsum[w] = inc;
    __syncthreads();
    if (w == 0){
      int s = (lane < 16) ? wsum[lane] : 0;
      int sc = s;
      #pragma unroll
      for (int d = 1; d < 16; d <<= 1){
        int t = __shfl_up(sc, d);
        if (lane >= d) sc += t;
      }
      if (lane < 16) woff[lane] = sc - s;
    }
    __syncthreads();
    int excl = carry_s + woff[w] + (inc - v);
    if (i < N) offs[i] = excl;
    __syncthreads();
    if (threadIdx.x == 1023) carry_s = excl + v;
    __syncthreads();
  }
  if (threadIdx.x == 0) offs[N] = carry_s;
}

// ---------------- CSR fill (augmented edges: [0,E) original, [E,E+N) self-loops) ----------------
__global__ void fill_kernel(const int* __restrict__ ei, const int* __restrict__ offs,
                            int* __restrict__ cursor, int* __restrict__ csr, int E, int N)
{
  int e = blockIdx.x*256 + threadIdx.x;
  int Ea = E + N;
  if (e >= Ea) return;
  int dst = (e < E) ? ei[E + e] : (e - E);
  int p = atomicAdd(cursor + dst, 1);
  csr[offs[dst] + p] = e;
}

// ---------------- xl = h@Wl+bl, xr = h@Wr+br (in-place safe for hin==xlo) ----------------
__global__ __launch_bounds__(256) void xfrm_kernel(
    const float* hin,
    const float* __restrict__ Wl, const float* __restrict__ bl,
    const float* __restrict__ Wr, const float* __restrict__ br,
    float* xlo, float* __restrict__ xro, int N)
{
  __shared__ float sWl[4096], sWr[4096], sbl[64], sbr[64];
  for (int i=threadIdx.x;i<4096;i+=256){ sWl[i]=Wl[i]; sWr[i]=Wr[i]; }
  if (threadIdx.x<64){ sbl[threadIdx.x]=bl[threadIdx.x]; sbr[threadIdx.x]=br[threadIdx.x]; }
  __syncthreads();
  int lane=threadIdx.x&63;
  int n0=(blockIdx.x*4+(threadIdx.x>>6))*4;
  if (n0>=N) return;
  float hv[4];
  #pragma unroll
  for (int m=0;m<4;m++){ int n=n0+m; hv[m]=(n<N)? hin[(size_t)n*64+lane]:0.f; }
  float al[4], ar[4];
  #pragma unroll
  for (int m=0;m<4;m++){ al[m]=sbl[lane]; ar[m]=sbr[lane]; }
  for (int k=0;k<64;k++){
    float wl=sWl[k*64+lane], wr=sWr[k*64+lane];
    #pragma unroll
    for (int m=0;m<4;m++){ float a=__shfl(hv[m],k); al[m]+=a*wl; ar[m]+=a*wr; }
  }
  #pragma unroll
  for (int m=0;m<4;m++){
    int n=n0+m;
    if (n<N){ xlo[(size_t)n*64+lane]=al[m]; xro[(size_t)n*64+lane]=ar[m]; }
  }
}

// ---------------- fused GATv2 layer: wave per dst node ----------------
// lane = h*16 + c. loop1: e-scores -> aout + running max. loop2: segment sum.
// loop3: alpha (written to aout) + message accumulation.
__global__ __launch_bounds__(256) void gat_kernel(
    const int* __restrict__ ei, const int* __restrict__ offs, const int* __restrict__ csr,
    const float* __restrict__ eattr, const float* __restrict__ lattr,
    const float* __restrict__ xl, const float* __restrict__ xr,
    const float* __restrict__ We, const float* __restrict__ att,
    const float* __restrict__ bias,
    float* aout, float* __restrict__ hout,
    int E, int N, int do_relu)
{
  int lane = threadIdx.x & 63;
  int n = blockIdx.x*4 + (threadIdx.x>>6);
  if (n >= N) return;
  float we0=We[0*64+lane], we1=We[1*64+lane], we2=We[2*64+lane],
        we3=We[3*64+lane], we4=We[4*64+lane], we5=We[5*64+lane];
  float attv = att[lane];
  float bv = bias[lane];
  float xrv = xr[(size_t)n*64+lane];
  int h = lane >> 4;
  bool isbase = (lane & 15) == 0;
  int o0 = offs[n], o1 = offs[n+1];
  float mmax = -3.402823e38f;
  for (int o = o0; o < o1; ++o){
    int e = csr[o];
    int src; const float* ep;
    if (e < E){ src = ei[e]; ep = eattr + (size_t)e*6; }
    else      { src = e - E; ep = lattr + (size_t)src*6; }
    float ev = (lane < 6) ? ep[lane] : 0.f;
    float s = xl[(size_t)src*64+lane] + xrv;
    s += __shfl(ev,0)*we0; s += __shfl(ev,1)*we1; s += __shfl(ev,2)*we2;
    s += __shfl(ev,3)*we3; s += __shfl(ev,4)*we4; s += __shfl(ev,5)*we5;
    float g = (s > 0.f) ? s : NEG*s;
    float p = g * attv;
    p += __shfl_xor(p,1); p += __shfl_xor(p,2); p += __shfl_xor(p,4); p += __shfl_xor(p,8);
    if (isbase) aout[(size_t)e*4 + h] = p;   // store raw score e
    mmax = fmaxf(mmax, p);                   // p replicated within 16-lane group
  }
  // make our own stores visible to our own subsequent loads
  asm volatile("s_waitcnt vmcnt(0)" ::: "memory");
  float ssum = 0.f;
  for (int o = o0; o < o1; ++o){
    int e = csr[o];
    float evv = aout[(size_t)e*4 + h];
    ssum += __expf(evv - mmax);
  }
  float sinv = 1.f/(ssum + 1e-16f);
  float acc = 0.f;
  for (int o = o0; o < o1; ++o){
    int e = csr[o];
    int src = (e < E) ? ei[e] : (e - E);
    float evv = aout[(size_t)e*4 + h];
    float al = __expf(evv - mmax) * sinv;
    if (isbase) aout[(size_t)e*4 + h] = al;  // final alpha
    acc += al * xl[(size_t)src*64+lane];
  }
  float outv = acc + bv;
  if (do_relu) outv = fmaxf(outv, 0.f);
  hout[(size_t)n*64+lane] = outv;
}

// ---------------- GRU (n < T) + copy (T <= n < N), 8 nodes per wave ----------------
__global__ __launch_bounds__(256) void gru_kernel(
    const float* __restrict__ h2, const float* __restrict__ hid,
    const float* __restrict__ Wi, const float* __restrict__ bi,
    const float* __restrict__ Wh, const float* __restrict__ bh,
    const int* __restrict__ Tptr, float* __restrict__ nf, int N)
{
  int lane = threadIdx.x & 63;
  int T = *Tptr;
  int n0 = (blockIdx.x*4 + (threadIdx.x>>6))*8;
  if (n0 >= N) return;
  float hv[8];
  #pragma unroll
  for (int m=0;m<8;m++){ int n=n0+m; hv[m] = (n<N)? h2[(size_t)n*64+lane] : 0.f; }
  if (n0 >= T){
    #pragma unroll
    for (int m=0;m<8;m++){ int n=n0+m; if (n<N) nf[(size_t)n*64+lane]=hv[m]; }
    return;
  }
  float pv[8];
  #pragma unroll
  for (int m=0;m<8;m++){ int n=n0+m; pv[m] = (n<T)? hid[(size_t)n*64+lane] : 0.f; }
  float gr[8],gz[8],gn[8],hr[8],hz[8],hn[8];
  #pragma unroll
  for (int m=0;m<8;m++){ gr[m]=0.f;gz[m]=0.f;gn[m]=0.f;hr[m]=0.f;hz[m]=0.f;hn[m]=0.f; }
  for (int k=0;k<64;k++){
    float wir=Wi[k*192+lane], wiz=Wi[k*192+64+lane], win=Wi[k*192+128+lane];
    float whr=Wh[k*192+lane], whz=Wh[k*192+64+lane], whn=Wh[k*192+128+lane];
    #pragma unroll
    for (int m=0;m<8;m++){
      float a=__shfl(hv[m],k), b=__shfl(pv[m],k);
      gr[m]+=a*wir; gz[m]+=a*wiz; gn[m]+=a*win;
      hr[m]+=b*whr; hz[m]+=b*whz; hn[m]+=b*whn;
    }
  }
  float bir=bi[lane], biz=bi[64+lane], bin=bi[128+lane];
  float bhr=bh[lane], bhz=bh[64+lane], bhn=bh[128+lane];
  #pragma unroll
  for (int m=0;m<8;m++){
    int n=n0+m;
    if (n<T){
      float r  = sigmoidf_(gr[m]+bir + hr[m]+bhr);
      float z  = sigmoidf_(gz[m]+biz + hz[m]+bhz);
      float nn = tanhf(gn[m]+bin + r*(hn[m]+bhn));
      nf[(size_t)n*64+lane] = (1.f-z)*nn + z*pv[m];
    } else if (n<N){
      nf[(size_t)n*64+lane] = hv[m];
    }
  }
}

// ---------------- decoder ----------------
__global__ __launch_bounds__(256) void dec_kernel(
    const float* __restrict__ nf, const float* __restrict__ x, const float* __restrict__ pos,
    const float* __restrict__ W1, const float* __restrict__ b1,
    const float* __restrict__ W2, const float* __restrict__ b2,
    float* __restrict__ fout, int N)
{
  __shared__ float sW1[64*64];
  __shared__ float sW2[64*7];
  __shared__ float sb1[64];
  __shared__ float sb2[7];
  for (int i=threadIdx.x;i<64*64;i+=256) sW1[i]=W1[i];
  for (int i=threadIdx.x;i<64*7;i+=256) sW2[i]=W2[i];
  if (threadIdx.x<64) sb1[threadIdx.x]=b1[threadIdx.x];
  if (threadIdx.x<7)  sb2[threadIdx.x]=b2[threadIdx.x];
  __syncthreads();
  int lane = threadIdx.x & 63;
  int n0 = (blockIdx.x*4 + (threadIdx.x>>6))*4;
  if (n0>=N) return;
  float hv[4];
  #pragma unroll
  for (int m=0;m<4;m++){ int n=n0+m; hv[m]=(n<N)? nf[(size_t)n*64+lane] : 0.f; }
  float t[4];
  #pragma unroll
  for (int m=0;m<4;m++) t[m]=sb1[lane];
  for (int k=0;k<64;k++){
    float w=sW1[k*64+lane];
    #pragma unroll
    for (int m=0;m<4;m++) t[m] += __shfl(hv[m],k)*w;
  }
  #pragma unroll
  for (int m=0;m<4;m++) t[m]=fmaxf(t[m],0.f);
  #pragma unroll
  for (int c=0;c<7;c++){
    float w = sW2[lane*7+c];
    float p0=t[0]*w, p1=t[1]*w, p2=t[2]*w, p3=t[3]*w;
    #pragma unroll
    for (int d=1;d<64;d<<=1){
      p0+=__shfl_xor(p0,d); p1+=__shfl_xor(p1,d); p2+=__shfl_xor(p2,d); p3+=__shfl_xor(p3,d);
    }
    if (lane==c){
      float b = sb2[c];
      float pm[4]={p0,p1,p2,p3};
      #pragma unroll
      for (int m=0;m<4;m++){
        int n=n0+m;
        if (n<N){
          float val = pm[m]+b;
          if (c<3)      val += pos[(size_t)n*3+c];
          else if (c<6) val += x[(size_t)n*7+(c-3)];
          fout[(size_t)n*7+c] = val;
        }
      }
    }
  }
}

extern "C" void kernel_launch(void* const* d_in, const int* in_sizes, int n_in,
                              void* d_out, int out_size, void* d_ws, size_t ws_size,
                              hipStream_t stream)
{
  const float* x     = (const float*)d_in[0];
  const float* pos   = (const float*)d_in[1];
  const int*   ntype = (const int*)d_in[2];
  const int*   eidx  = (const int*)d_in[3];
  const float* eattr = (const float*)d_in[4];
  const int*   Tptr  = (const int*)d_in[5];
  const float* hid   = (const float*)d_in[6];
  const float* temb  = (const float*)d_in[7];
  const float* encW1 = (const float*)d_in[8];
  const float* encb1 = (const float*)d_in[9];
  const float* encW2 = (const float*)d_in[10];
  const float* encb2 = (const float*)d_in[11];
  const float* gruWi = (const float*)d_in[12];
  const float* grubi = (const float*)d_in[13];
  const float* gruWh = (const float*)d_in[14];
  const float* grubh = (const float*)d_in[15];
  const float* decW1 = (const float*)d_in[16];
  const float* decb1 = (const float*)d_in[17];
  const float* decW2 = (const float*)d_in[18];
  const float* decb2 = (const float*)d_in[19];
  const float* gWl[2]  = {(const float*)d_in[20], (const float*)d_in[27]};
  const float* gbl[2]  = {(const float*)d_in[21], (const float*)d_in[28]};
  const float* gWr[2]  = {(const float*)d_in[22], (const float*)d_in[29]};
  const float* gbr[2]  = {(const float*)d_in[23], (const float*)d_in[30]};
  const float* gWe[2]  = {(const float*)d_in[24], (const float*)d_in[31]};
  const float* gatt[2] = {(const float*)d_in[25], (const float*)d_in[32]};
  const float* gbias[2]= {(const float*)d_in[26], (const float*)d_in[33]};

  int N  = in_sizes[0] / 7;
  int E  = in_sizes[3] / 2;
  int Ea = E + N;

  char* w = (char*)d_ws;
  float* A      = (float*)w; w += (size_t)N*64*sizeof(float);
  float* B      = (float*)w; w += (size_t)N*64*sizeof(float);
  float* C      = (float*)w; w += (size_t)N*64*sizeof(float);
  int*   deg    = (int*)w;   w += (size_t)N*sizeof(int);
  float* lattr  = (float*)w; w += (size_t)N*6*sizeof(float);
  int*   offs   = (int*)w;   w += (size_t)(N+1)*sizeof(int);
  int*   cursor = (int*)w;   w += (size_t)N*sizeof(int);
  int*   csr    = (int*)w;   w += (size_t)Ea*sizeof(int);

  float* out_final = (float*)d_out;
  float* out_nf    = out_final + (size_t)N*7;
  float* out_a1    = out_nf + (size_t)N*64;
  float* out_a2    = out_a1 + (size_t)Ea*4;

  hipMemsetAsync(deg,    0, (size_t)N*sizeof(int),     stream);
  hipMemsetAsync(lattr,  0, (size_t)N*6*sizeof(float), stream);
  hipMemsetAsync(cursor, 0, (size_t)N*sizeof(int),     stream);

  enc_kernel<<<(N+15)/16, 256, 0, stream>>>(x,pos,ntype,temb,encW1,encb1,encW2,encb2,A,N);
  deg_kernel<<<(E+255)/256, 256, 0, stream>>>(eidx, eattr, deg, lattr, E);
  lnorm_kernel<<<(N+255)/256, 256, 0, stream>>>(deg, lattr, N);
  scan_kernel<<<1, 1024, 0, stream>>>(deg, offs, N);
  fill_kernel<<<(Ea+255)/256, 256, 0, stream>>>(eidx, offs, cursor, csr, E, N);

  // layer 1: h(A) -> xl(A, in-place), xr(C); out h1 -> B (relu)
  xfrm_kernel<<<(N+15)/16, 256, 0, stream>>>(A, gWl[0], gbl[0], gWr[0], gbr[0], A, C, N);
  gat_kernel<<<(N+3)/4, 256, 0, stream>>>(eidx, offs, csr, eattr, lattr, A, C,
      gWe[0], gatt[0], gbias[0], out_a1, B, E, N, 1);
  // layer 2: h1(B) -> xl(B, in-place), xr(C); out h2 -> A (no relu)
  xfrm_kernel<<<(N+15)/16, 256, 0, stream>>>(B, gWl[1], gbl[1], gWr[1], gbr[1], B, C, N);
  gat_kernel<<<(N+3)/4, 256, 0, stream>>>(eidx, offs, csr, eattr, lattr, B, C,
      gWe[1], gatt[1], gbias[1], out_a2, A, E, N, 0);

  gru_kernel<<<(N+31)/32, 256, 0, stream>>>(A, hid, gruWi, grubi, gruWh, grubh, Tptr, out_nf, N);
  dec_kernel<<<(N+15)/16, 256, 0, stream>>>(out_nf, x, pos, decW1, decb1, decW2, decb2, out_final, N);
}

// Round 2
// 1487.709 us; speedup vs baseline: 1.4400x; 1.4400x over previous
//
#include <hip/hip_runtime.h>

#define NEG 0.2f

__device__ __forceinline__ float sigmoidf_(float v){ return 1.f/(1.f+__expf(-v)); }

// ---------------- encoder: h = relu([x,pos,temb[nt]] @ W1 + b1) @ W2 + b2 ----------------
__global__ __launch_bounds__(256) void enc_kernel(
    const float* __restrict__ x, const float* __restrict__ pos,
    const int* __restrict__ ntype, const float* __restrict__ temb,
    const float* __restrict__ W1, const float* __restrict__ b1,
    const float* __restrict__ W2, const float* __restrict__ b2,
    float* __restrict__ hout, int N)
{
  __shared__ float sW1[18*64];
  __shared__ float sW2[64*64];
  __shared__ float sb1[64], sb2[64];
  for (int i=threadIdx.x; i<18*64; i+=256) sW1[i]=W1[i];
  for (int i=threadIdx.x; i<64*64; i+=256) sW2[i]=W2[i];
  if (threadIdx.x<64){ sb1[threadIdx.x]=b1[threadIdx.x]; sb2[threadIdx.x]=b2[threadIdx.x]; }
  __syncthreads();
  int lane = threadIdx.x & 63;
  int n0 = (blockIdx.x*4 + (threadIdx.x>>6))*4;
  if (n0 >= N) return;
  float f[4];
  #pragma unroll
  for (int m=0;m<4;m++){
    int n=n0+m; f[m]=0.f;
    if (n<N){
      if (lane<7)       f[m]=x[(size_t)n*7+lane];
      else if (lane<10) f[m]=pos[(size_t)n*3+lane-7];
      else if (lane<18) f[m]=temb[ntype[n]*8+lane-10];
    }
  }
  float t[4];
  #pragma unroll
  for (int m=0;m<4;m++) t[m]=sb1[lane];
  for (int k=0;k<18;k++){
    float w=sW1[k*64+lane];
    #pragma unroll
    for (int m=0;m<4;m++) t[m] += __shfl(f[m],k)*w;
  }
  #pragma unroll
  for (int m=0;m<4;m++) t[m]=fmaxf(t[m],0.f);
  float o[4];
  #pragma unroll
  for (int m=0;m<4;m++) o[m]=sb2[lane];
  for (int k=0;k<64;k++){
    float w=sW2[k*64+lane];
    #pragma unroll
    for (int m=0;m<4;m++) o[m] += __shfl(t[m],k)*w;
  }
  #pragma unroll
  for (int m=0;m<4;m++){ int n=n0+m; if (n<N) hout[(size_t)n*64+lane]=o[m]; }
}

// ---------------- degree only (int atomics; attr sums moved to lattr_kernel) ----------------
__global__ void deg_kernel(const int* __restrict__ ei, int* __restrict__ deg, int E)
{
  int e = blockIdx.x*256 + threadIdx.x;
  if (e>=E) return;
  atomicAdd(deg + ei[E+e], 1);
}

// ---------------- exclusive scan of (deg+1) -> offs[N+1], single block ----------------
__global__ __launch_bounds__(1024) void scan_kernel(const int* __restrict__ deg, int* __restrict__ offs, int N)
{
  __shared__ int wsum[16];
  __shared__ int woff[16];
  __shared__ int carry_s;
  int lane = threadIdx.x & 63;
  int w = threadIdx.x >> 6;
  if (threadIdx.x == 0) carry_s = 0;
  __syncthreads();
  for (int base = 0; base < N; base += 1024){
    int i = base + (int)threadIdx.x;
    int v = (i < N) ? (deg[i] + 1) : 0;
    int inc = v;
    #pragma unroll
    for (int d = 1; d < 64; d <<= 1){
      int t = __shfl_up(inc, d);
      if (lane >= d) inc += t;
    }
    if (lane == 63) wsum[w] = inc;
    __syncthreads();
    if (w == 0){
      int s = (lane < 16) ? wsum[lane] : 0;
      int sc = s;
      #pragma unroll
      for (int d = 1; d < 16; d <<= 1){
        int t = __shfl_up(sc, d);
        if (lane >= d) sc += t;
      }
      if (lane < 16) woff[lane] = sc - s;
    }
    __syncthreads();
    int excl = carry_s + woff[w] + (inc - v);
    if (i < N) offs[i] = excl;
    __syncthreads();
    if (threadIdx.x == 1023) carry_s = excl + v;
    __syncthreads();
  }
  if (threadIdx.x == 0) offs[N] = carry_s;
}

// ---------------- CSR fill (augmented edges: [0,E) original, [E,E+N) self-loops) ----------------
__global__ void fill_kernel(const int* __restrict__ ei, const int* __restrict__ offs,
                            int* __restrict__ cursor, int* __restrict__ csr, int E, int N)
{
  int e = blockIdx.x*256 + threadIdx.x;
  int Ea = E + N;
  if (e >= Ea) return;
  int dst = (e < E) ? ei[E + e] : (e - E);
  int p = atomicAdd(cursor + dst, 1);
  csr[offs[dst] + p] = e;
}

// ---------------- loop_attr: per-node CSR gather (no float atomics) ----------------
__global__ void lattr_kernel(const int* __restrict__ offs, const int* __restrict__ csr,
                             const float* __restrict__ eattr, float* __restrict__ lattr,
                             int E, int N)
{
  int n = blockIdx.x*256 + threadIdx.x;
  if (n>=N) return;
  float a0=0.f,a1=0.f,a2=0.f,a3=0.f,a4=0.f,a5=0.f;
  int cnt=0;
  int o1 = offs[n+1];
  for (int o=offs[n]; o<o1; ++o){
    int e = csr[o];
    if (e >= E) continue;               // skip self-loop slot
    const float* ep = eattr + (size_t)e*6;
    a0+=ep[0]; a1+=ep[1]; a2+=ep[2]; a3+=ep[3]; a4+=ep[4]; a5+=ep[5];
    cnt++;
  }
  float inv = 1.f/fmaxf((float)cnt,1.f);
  float* lp = lattr + (size_t)n*6;
  lp[0]=a0*inv; lp[1]=a1*inv; lp[2]=a2*inv; lp[3]=a3*inv; lp[4]=a4*inv; lp[5]=a5*inv;
}

// ---------------- xl = h@Wl+bl, xr = h@Wr+br (in-place safe for hin==xlo) ----------------
__global__ __launch_bounds__(256) void xfrm_kernel(
    const float* hin,
    const float* __restrict__ Wl, const float* __restrict__ bl,
    const float* __restrict__ Wr, const float* __restrict__ br,
    float* xlo, float* __restrict__ xro, int N)
{
  __shared__ float sWl[4096], sWr[4096], sbl[64], sbr[64];
  for (int i=threadIdx.x;i<4096;i+=256){ sWl[i]=Wl[i]; sWr[i]=Wr[i]; }
  if (threadIdx.x<64){ sbl[threadIdx.x]=bl[threadIdx.x]; sbr[threadIdx.x]=br[threadIdx.x]; }
  __syncthreads();
  int lane=threadIdx.x&63;
  int n0=(blockIdx.x*4+(threadIdx.x>>6))*4;
  if (n0>=N) return;
  float hv[4];
  #pragma unroll
  for (int m=0;m<4;m++){ int n=n0+m; hv[m]=(n<N)? hin[(size_t)n*64+lane]:0.f; }
  float al[4], ar[4];
  #pragma unroll
  for (int m=0;m<4;m++){ al[m]=sbl[lane]; ar[m]=sbr[lane]; }
  for (int k=0;k<64;k++){
    float wl=sWl[k*64+lane], wr=sWr[k*64+lane];
    #pragma unroll
    for (int m=0;m<4;m++){ float a=__shfl(hv[m],k); al[m]+=a*wl; ar[m]+=a*wr; }
  }
  #pragma unroll
  for (int m=0;m<4;m++){
    int n=n0+m;
    if (n<N){ xlo[(size_t)n*64+lane]=al[m]; xro[(size_t)n*64+lane]=ar[m]; }
  }
}

// ---------------- fused GATv2 layer: wave per dst node, flash-style online softmax ----------------
// lane = h*16 + c. Single pass over edges: gather xl[src] ONCE, online (m,s,acc),
// store raw score to aout. Mini-pass 2 converts raw scores to alpha in place
// (touches only aout, 4 active lanes, no xl gather).
__global__ __launch_bounds__(256) void gat_kernel(
    const int* __restrict__ ei, const int* __restrict__ offs, const int* __restrict__ csr,
    const float* __restrict__ eattr, const float* __restrict__ lattr,
    const float* __restrict__ xl, const float* __restrict__ xr,
    const float* __restrict__ We, const float* __restrict__ att,
    const float* __restrict__ bias,
    float* aout, float* __restrict__ hout,
    int E, int N, int do_relu)
{
  int lane = threadIdx.x & 63;
  int n = blockIdx.x*4 + (threadIdx.x>>6);
  if (n >= N) return;
  float we0=We[0*64+lane], we1=We[1*64+lane], we2=We[2*64+lane],
        we3=We[3*64+lane], we4=We[4*64+lane], we5=We[5*64+lane];
  float attv = att[lane];
  float bv = bias[lane];
  float xrv = xr[(size_t)n*64+lane];
  int h = lane >> 4;
  bool isbase = (lane & 15) == 0;
  int o0 = offs[n], o1 = offs[n+1];
  float mmax = -3.402823e38f;
  float ssum = 0.f;
  float acc  = 0.f;
  for (int o = o0; o < o1; ++o){
    int e = csr[o];
    int src; const float* ep;
    if (e < E){ src = ei[e]; ep = eattr + (size_t)e*6; }
    else      { src = e - E; ep = lattr + (size_t)src*6; }
    float ev = (lane < 6) ? ep[lane] : 0.f;
    float xv = xl[(size_t)src*64+lane];
    float s = xv + xrv;
    s += __shfl(ev,0)*we0; s += __shfl(ev,1)*we1; s += __shfl(ev,2)*we2;
    s += __shfl(ev,3)*we3; s += __shfl(ev,4)*we4; s += __shfl(ev,5)*we5;
    float g = (s > 0.f) ? s : NEG*s;
    float p = g * attv;
    p += __shfl_xor(p,1); p += __shfl_xor(p,2); p += __shfl_xor(p,4); p += __shfl_xor(p,8);
    if (isbase) aout[(size_t)e*4 + h] = p;   // raw score
    // online softmax update (m,s,p replicated within each 16-lane head group)
    float mnew  = fmaxf(mmax, p);
    float scale = __expf(mmax - mnew);       // first iter: exp(-inf) = 0
    float wgt   = __expf(p - mnew);
    ssum = ssum*scale + wgt;
    acc  = acc *scale + wgt*xv;
    mmax = mnew;
  }
  float sinv = 1.f/(ssum + 1e-16f);
  // make our own raw-score stores visible to our own loads
  asm volatile("s_waitcnt vmcnt(0)" ::: "memory");
  for (int o = o0; o < o1; ++o){
    int e = csr[o];
    if (isbase){
      float evv = aout[(size_t)e*4 + h];
      aout[(size_t)e*4 + h] = __expf(evv - mmax) * sinv;
    }
  }
  float outv = acc*sinv + bv;
  if (do_relu) outv = fmaxf(outv, 0.f);
  hout[(size_t)n*64+lane] = outv;
}

// ---------------- GRU (n < T) + copy (T <= n < N), 8 nodes per wave ----------------
__global__ __launch_bounds__(256) void gru_kernel(
    const float* __restrict__ h2, const float* __restrict__ hid,
    const float* __restrict__ Wi, const float* __restrict__ bi,
    const float* __restrict__ Wh, const float* __restrict__ bh,
    const int* __restrict__ Tptr, float* __restrict__ nf, int N)
{
  int lane = threadIdx.x & 63;
  int T = *Tptr;
  int n0 = (blockIdx.x*4 + (threadIdx.x>>6))*8;
  if (n0 >= N) return;
  float hv[8];
  #pragma unroll
  for (int m=0;m<8;m++){ int n=n0+m; hv[m] = (n<N)? h2[(size_t)n*64+lane] : 0.f; }
  if (n0 >= T){
    #pragma unroll
    for (int m=0;m<8;m++){ int n=n0+m; if (n<N) nf[(size_t)n*64+lane]=hv[m]; }
    return;
  }
  float pv[8];
  #pragma unroll
  for (int m=0;m<8;m++){ int n=n0+m; pv[m] = (n<T)? hid[(size_t)n*64+lane] : 0.f; }
  float gr[8],gz[8],gn[8],hr[8],hz[8],hn[8];
  #pragma unroll
  for (int m=0;m<8;m++){ gr[m]=0.f;gz[m]=0.f;gn[m]=0.f;hr[m]=0.f;hz[m]=0.f;hn[m]=0.f; }
  for (int k=0;k<64;k++){
    float wir=Wi[k*192+lane], wiz=Wi[k*192+64+lane], win=Wi[k*192+128+lane];
    float whr=Wh[k*192+lane], whz=Wh[k*192+64+lane], whn=Wh[k*192+128+lane];
    #pragma unroll
    for (int m=0;m<8;m++){
      float a=__shfl(hv[m],k), b=__shfl(pv[m],k);
      gr[m]+=a*wir; gz[m]+=a*wiz; gn[m]+=a*win;
      hr[m]+=b*whr; hz[m]+=b*whz; hn[m]+=b*whn;
    }
  }
  float bir=bi[lane], biz=bi[64+lane], bin=bi[128+lane];
  float bhr=bh[lane], bhz=bh[64+lane], bhn=bh[128+lane];
  #pragma unroll
  for (int m=0;m<8;m++){
    int n=n0+m;
    if (n<T){
      float r  = sigmoidf_(gr[m]+bir + hr[m]+bhr);
      float z  = sigmoidf_(gz[m]+biz + hz[m]+bhz);
      float nn = tanhf(gn[m]+bin + r*(hn[m]+bhn));
      nf[(size_t)n*64+lane] = (1.f-z)*nn + z*pv[m];
    } else if (n<N){
      nf[(size_t)n*64+lane] = hv[m];
    }
  }
}

// ---------------- decoder ----------------
__global__ __launch_bounds__(256) void dec_kernel(
    const float* __restrict__ nf, const float* __restrict__ x, const float* __restrict__ pos,
    const float* __restrict__ W1, const float* __restrict__ b1,
    const float* __restrict__ W2, const float* __restrict__ b2,
    float* __restrict__ fout, int N)
{
  __shared__ float sW1[64*64];
  __shared__ float sW2[64*7];
  __shared__ float sb1[64];
  __shared__ float sb2[7];
  for (int i=threadIdx.x;i<64*64;i+=256) sW1[i]=W1[i];
  for (int i=threadIdx.x;i<64*7;i+=256) sW2[i]=W2[i];
  if (threadIdx.x<64) sb1[threadIdx.x]=b1[threadIdx.x];
  if (threadIdx.x<7)  sb2[threadIdx.x]=b2[threadIdx.x];
  __syncthreads();
  int lane = threadIdx.x & 63;
  int n0 = (blockIdx.x*4 + (threadIdx.x>>6))*4;
  if (n0>=N) return;
  float hv[4];
  #pragma unroll
  for (int m=0;m<4;m++){ int n=n0+m; hv[m]=(n<N)? nf[(size_t)n*64+lane] : 0.f; }
  float t[4];
  #pragma unroll
  for (int m=0;m<4;m++) t[m]=sb1[lane];
  for (int k=0;k<64;k++){
    float w=sW1[k*64+lane];
    #pragma unroll
    for (int m=0;m<4;m++) t[m] += __shfl(hv[m],k)*w;
  }
  #pragma unroll
  for (int m=0;m<4;m++) t[m]=fmaxf(t[m],0.f);
  #pragma unroll
  for (int c=0;c<7;c++){
    float w = sW2[lane*7+c];
    float p0=t[0]*w, p1=t[1]*w, p2=t[2]*w, p3=t[3]*w;
    #pragma unroll
    for (int d=1;d<64;d<<=1){
      p0+=__shfl_xor(p0,d); p1+=__shfl_xor(p1,d); p2+=__shfl_xor(p2,d); p3+=__shfl_xor(p3,d);
    }
    if (lane==c){
      float b = sb2[c];
      float pm[4]={p0,p1,p2,p3};
      #pragma unroll
      for (int m=0;m<4;m++){
        int n=n0+m;
        if (n<N){
          float val = pm[m]+b;
          if (c<3)      val += pos[(size_t)n*3+c];
          else if (c<6) val += x[(size_t)n*7+(c-3)];
          fout[(size_t)n*7+c] = val;
        }
      }
    }
  }
}

extern "C" void kernel_launch(void* const* d_in, const int* in_sizes, int n_in,
                              void* d_out, int out_size, void* d_ws, size_t ws_size,
                              hipStream_t stream)
{
  const float* x     = (const float*)d_in[0];
  const float* pos   = (const float*)d_in[1];
  const int*   ntype = (const int*)d_in[2];
  const int*   eidx  = (const int*)d_in[3];
  const float* eattr = (const float*)d_in[4];
  const int*   Tptr  = (const int*)d_in[5];
  const float* hid   = (const float*)d_in[6];
  const float* temb  = (const float*)d_in[7];
  const float* encW1 = (const float*)d_in[8];
  const float* encb1 = (const float*)d_in[9];
  const float* encW2 = (const float*)d_in[10];
  const float* encb2 = (const float*)d_in[11];
  const float* gruWi = (const float*)d_in[12];
  const float* grubi = (const float*)d_in[13];
  const float* gruWh = (const float*)d_in[14];
  const float* grubh = (const float*)d_in[15];
  const float* decW1 = (const float*)d_in[16];
  const float* decb1 = (const float*)d_in[17];
  const float* decW2 = (const float*)d_in[18];
  const float* decb2 = (const float*)d_in[19];
  const float* gWl[2]  = {(const float*)d_in[20], (const float*)d_in[27]};
  const float* gbl[2]  = {(const float*)d_in[21], (const float*)d_in[28]};
  const float* gWr[2]  = {(const float*)d_in[22], (const float*)d_in[29]};
  const float* gbr[2]  = {(const float*)d_in[23], (const float*)d_in[30]};
  const float* gWe[2]  = {(const float*)d_in[24], (const float*)d_in[31]};
  const float* gatt[2] = {(const float*)d_in[25], (const float*)d_in[32]};
  const float* gbias[2]= {(const float*)d_in[26], (const float*)d_in[33]};

  int N  = in_sizes[0] / 7;
  int E  = in_sizes[3] / 2;
  int Ea = E + N;

  char* w = (char*)d_ws;
  float* A      = (float*)w; w += (size_t)N*64*sizeof(float);
  float* B      = (float*)w; w += (size_t)N*64*sizeof(float);
  float* C      = (float*)w; w += (size_t)N*64*sizeof(float);
  int*   deg    = (int*)w;   w += (size_t)N*sizeof(int);
  float* lattr  = (float*)w; w += (size_t)N*6*sizeof(float);
  int*   offs   = (int*)w;   w += (size_t)(N+1)*sizeof(int);
  int*   cursor = (int*)w;   w += (size_t)N*sizeof(int);
  int*   csr    = (int*)w;   w += (size_t)Ea*sizeof(int);

  float* out_final = (float*)d_out;
  float* out_nf    = out_final + (size_t)N*7;
  float* out_a1    = out_nf + (size_t)N*64;
  float* out_a2    = out_a1 + (size_t)Ea*4;

  hipMemsetAsync(deg,    0, (size_t)N*sizeof(int), stream);
  hipMemsetAsync(cursor, 0, (size_t)N*sizeof(int), stream);

  enc_kernel<<<(N+15)/16, 256, 0, stream>>>(x,pos,ntype,temb,encW1,encb1,encW2,encb2,A,N);
  deg_kernel<<<(E+255)/256, 256, 0, stream>>>(eidx, deg, E);
  scan_kernel<<<1, 1024, 0, stream>>>(deg, offs, N);
  fill_kernel<<<(Ea+255)/256, 256, 0, stream>>>(eidx, offs, cursor, csr, E, N);
  lattr_kernel<<<(N+255)/256, 256, 0, stream>>>(offs, csr, eattr, lattr, E, N);

  // layer 1: h(A) -> xl(A, in-place), xr(C); out h1 -> B (relu)
  xfrm_kernel<<<(N+15)/16, 256, 0, stream>>>(A, gWl[0], gbl[0], gWr[0], gbr[0], A, C, N);
  gat_kernel<<<(N+3)/4, 256, 0, stream>>>(eidx, offs, csr, eattr, lattr, A, C,
      gWe[0], gatt[0], gbias[0], out_a1, B, E, N, 1);
  // layer 2: h1(B) -> xl(B, in-place), xr(C); out h2 -> A (no relu)
  xfrm_kernel<<<(N+15)/16, 256, 0, stream>>>(B, gWl[1], gbl[1], gWr[1], gbr[1], B, C, N);
  gat_kernel<<<(N+3)/4, 256, 0, stream>>>(eidx, offs, csr, eattr, lattr, B, C,
      gWe[1], gatt[1], gbias[1], out_a2, A, E, N, 0);

  gru_kernel<<<(N+31)/32, 256, 0, stream>>>(A, hid, gruWi, grubi, gruWh, grubh, Tptr, out_nf, N);
  dec_kernel<<<(N+15)/16, 256, 0, stream>>>(out_nf, x, pos, decW1, decb1, decW2, decb2, out_final, N);
}

// Round 3
// 1026.776 us; speedup vs baseline: 2.0865x; 1.4489x over previous
//
#include <hip/hip_runtime.h>

#define NEG 0.2f
#define SCHUNK 1024

__device__ __forceinline__ float sigmoidf_(float v){ return 1.f/(1.f+__expf(-v)); }

// ---------------- encoder: h = relu([x,pos,temb[nt]] @ W1 + b1) @ W2 + b2 ----------------
__global__ __launch_bounds__(256) void enc_kernel(
    const float* __restrict__ x, const float* __restrict__ pos,
    const int* __restrict__ ntype, const float* __restrict__ temb,
    const float* __restrict__ W1, const float* __restrict__ b1,
    const float* __restrict__ W2, const float* __restrict__ b2,
    float* __restrict__ hout, int N)
{
  __shared__ float sW1[18*64];
  __shared__ float sW2[64*64];
  __shared__ float sb1[64], sb2[64];
  for (int i=threadIdx.x; i<18*64; i+=256) sW1[i]=W1[i];
  for (int i=threadIdx.x; i<64*64; i+=256) sW2[i]=W2[i];
  if (threadIdx.x<64){ sb1[threadIdx.x]=b1[threadIdx.x]; sb2[threadIdx.x]=b2[threadIdx.x]; }
  __syncthreads();
  int lane = threadIdx.x & 63;
  int n0 = (blockIdx.x*4 + (threadIdx.x>>6))*4;
  if (n0 >= N) return;
  float f[4];
  #pragma unroll
  for (int m=0;m<4;m++){
    int n=n0+m; f[m]=0.f;
    if (n<N){
      if (lane<7)       f[m]=x[(size_t)n*7+lane];
      else if (lane<10) f[m]=pos[(size_t)n*3+lane-7];
      else if (lane<18) f[m]=temb[ntype[n]*8+lane-10];
    }
  }
  float t[4];
  #pragma unroll
  for (int m=0;m<4;m++) t[m]=sb1[lane];
  for (int k=0;k<18;k++){
    float w=sW1[k*64+lane];
    #pragma unroll
    for (int m=0;m<4;m++) t[m] += __shfl(f[m],k)*w;
  }
  #pragma unroll
  for (int m=0;m<4;m++) t[m]=fmaxf(t[m],0.f);
  float o[4];
  #pragma unroll
  for (int m=0;m<4;m++) o[m]=sb2[lane];
  for (int k=0;k<64;k++){
    float w=sW2[k*64+lane];
    #pragma unroll
    for (int m=0;m<4;m++) o[m] += __shfl(t[m],k)*w;
  }
  #pragma unroll
  for (int m=0;m<4;m++){ int n=n0+m; if (n<N) hout[(size_t)n*64+lane]=o[m]; }
}

// ---------------- degree ----------------
__global__ void deg_kernel(const int* __restrict__ ei, int* __restrict__ deg, int E)
{
  int e = blockIdx.x*256 + threadIdx.x;
  if (e>=E) return;
  atomicAdd(deg + ei[E+e], 1);
}

// ---------------- 3-phase multi-block exclusive scan of (deg+1) -> offs[N] ----------------
__global__ __launch_bounds__(256) void scan_reduce(const int* __restrict__ deg, int* __restrict__ bsum, int N)
{
  int base = blockIdx.x*SCHUNK + threadIdx.x*4;
  int s=0;
  #pragma unroll
  for (int j=0;j<4;j++){ int i=base+j; s += (i<N)? deg[i]+1 : 0; }
  #pragma unroll
  for (int d=1;d<64;d<<=1) s += __shfl_xor(s,d);
  __shared__ int ws[4];
  if ((threadIdx.x&63)==0) ws[threadIdx.x>>6]=s;
  __syncthreads();
  if (threadIdx.x==0) bsum[blockIdx.x]=ws[0]+ws[1]+ws[2]+ws[3];
}

__global__ __launch_bounds__(1024) void scan_bsums(const int* __restrict__ bsum, int* __restrict__ bscan, int NB)
{
  int tid = threadIdx.x;
  int lane = tid&63, w = tid>>6;
  int v = (tid<NB)? bsum[tid] : 0;
  int inc = v;
  #pragma unroll
  for (int d=1;d<64;d<<=1){ int t=__shfl_up(inc,d); if (lane>=d) inc+=t; }
  __shared__ int wsum[16], woff[16];
  if (lane==63) wsum[w]=inc;
  __syncthreads();
  if (w==0){
    int s=(lane<16)?wsum[lane]:0; int sc=s;
    #pragma unroll
    for (int d=1;d<16;d<<=1){ int t=__shfl_up(sc,d); if (lane>=d) sc+=t; }
    if (lane<16) woff[lane]=sc-s;
  }
  __syncthreads();
  int excl = woff[w] + inc - v;
  if (tid<NB) bscan[tid]=excl;
}

__global__ __launch_bounds__(256) void scan_final(const int* __restrict__ deg, const int* __restrict__ bscan,
                                                  int* __restrict__ offs, int N)
{
  int lane = threadIdx.x&63, w = threadIdx.x>>6;
  int base = blockIdx.x*SCHUNK + threadIdx.x*4;
  int v[4]; int s=0;
  #pragma unroll
  for (int j=0;j<4;j++){ int i=base+j; v[j]=(i<N)?deg[i]+1:0; s+=v[j]; }
  int inc=s;
  #pragma unroll
  for (int d=1;d<64;d<<=1){ int t=__shfl_up(inc,d); if (lane>=d) inc+=t; }
  __shared__ int wsum[4], woff[4];
  if (lane==63) wsum[w]=inc;
  __syncthreads();
  if (threadIdx.x==0){ woff[0]=0; woff[1]=wsum[0]; woff[2]=wsum[0]+wsum[1]; woff[3]=wsum[0]+wsum[1]+wsum[2]; }
  __syncthreads();
  int excl = bscan[blockIdx.x] + woff[w] + (inc - s);
  #pragma unroll
  for (int j=0;j<4;j++){ int i=base+j; if (i<N) offs[i]=excl; excl+=v[j]; }
}

// ---------------- CSR fill: csr2[slot] = {edge_id, src}; self-loop pinned to LAST slot ----------------
__global__ void fill_kernel(const int* __restrict__ ei, const int* __restrict__ offs,
                            const int* __restrict__ deg, int* __restrict__ cursor,
                            int2* __restrict__ csr2, int E, int N)
{
  int e = blockIdx.x*256 + threadIdx.x;
  int Ea = E + N;
  if (e >= Ea) return;
  if (e < E){
    int dst = ei[E + e];
    int p = atomicAdd(cursor + dst, 1);
    csr2[offs[dst] + p] = make_int2(e, ei[e]);
  } else {
    int n = e - E;
    csr2[offs[n] + deg[n]] = make_int2(e, n);
  }
}

// ---------------- xl = h@Wl+bl, xr = h@Wr+br (in-place safe for hin==xlo) ----------------
__global__ __launch_bounds__(256) void xfrm_kernel(
    const float* hin,
    const float* __restrict__ Wl, const float* __restrict__ bl,
    const float* __restrict__ Wr, const float* __restrict__ br,
    float* xlo, float* __restrict__ xro, int N)
{
  __shared__ float sWl[4096], sWr[4096], sbl[64], sbr[64];
  for (int i=threadIdx.x;i<4096;i+=256){ sWl[i]=Wl[i]; sWr[i]=Wr[i]; }
  if (threadIdx.x<64){ sbl[threadIdx.x]=bl[threadIdx.x]; sbr[threadIdx.x]=br[threadIdx.x]; }
  __syncthreads();
  int lane=threadIdx.x&63;
  int n0=(blockIdx.x*4+(threadIdx.x>>6))*4;
  if (n0>=N) return;
  float hv[4];
  #pragma unroll
  for (int m=0;m<4;m++){ int n=n0+m; hv[m]=(n<N)? hin[(size_t)n*64+lane]:0.f; }
  float al[4], ar[4];
  #pragma unroll
  for (int m=0;m<4;m++){ al[m]=sbl[lane]; ar[m]=sbr[lane]; }
  for (int k=0;k<64;k++){
    float wl=sWl[k*64+lane], wr=sWr[k*64+lane];
    #pragma unroll
    for (int m=0;m<4;m++){ float a=__shfl(hv[m],k); al[m]+=a*wl; ar[m]+=a*wr; }
  }
  #pragma unroll
  for (int m=0;m<4;m++){
    int n=n0+m;
    if (n<N){ xlo[(size_t)n*64+lane]=al[m]; xro[(size_t)n*64+lane]=ar[m]; }
  }
}

// ---------------- fused GATv2 layer: wave per dst node, single-pass online softmax ----------------
// csr2 gives {e, src} directly (2-deep load chain), unrolled x4 for MLP.
// Self-loop is the LAST slot: its eattr is the running mean of the node's real
// in-edge attrs, accumulated from the ev values we already loaded.
#define EDGE_STEP(EIDX, EV, XV) do {                                         \
    float s_ = (XV) + xrv;                                                   \
    s_ += __shfl((EV),0)*we0; s_ += __shfl((EV),1)*we1;                      \
    s_ += __shfl((EV),2)*we2; s_ += __shfl((EV),3)*we3;                      \
    s_ += __shfl((EV),4)*we4; s_ += __shfl((EV),5)*we5;                      \
    float g_ = (s_>0.f)? s_ : NEG*s_;                                        \
    float p_ = g_*attv;                                                      \
    p_ += __shfl_xor(p_,1); p_ += __shfl_xor(p_,2);                          \
    p_ += __shfl_xor(p_,4); p_ += __shfl_xor(p_,8);                          \
    if (isbase) aout[(size_t)(EIDX)*4+h] = p_;                               \
    float mn_ = fmaxf(mmax,p_);                                              \
    float sc_ = __expf(mmax-mn_);                                            \
    float w_  = __expf(p_-mn_);                                              \
    ssum = ssum*sc_ + w_;                                                    \
    acc  = acc *sc_ + w_*(XV);                                               \
    mmax = mn_;                                                              \
  } while(0)

__global__ __launch_bounds__(256) void gat_kernel(
    const int2* __restrict__ csr2, const int* __restrict__ offs, const int* __restrict__ deg,
    const float* __restrict__ eattr,
    const float* __restrict__ xl, const float* __restrict__ xr,
    const float* __restrict__ We, const float* __restrict__ att,
    const float* __restrict__ bias,
    float* __restrict__ aout, float* __restrict__ mbuf, float* __restrict__ sbuf,
    float* __restrict__ hout,
    int E, int N, int do_relu)
{
  int lane = threadIdx.x & 63;
  int n = blockIdx.x*4 + (threadIdx.x>>6);
  if (n >= N) return;
  float we0=We[0*64+lane], we1=We[1*64+lane], we2=We[2*64+lane],
        we3=We[3*64+lane], we4=We[4*64+lane], we5=We[5*64+lane];
  float attv = att[lane];
  float bv = bias[lane];
  float xrv = xr[(size_t)n*64+lane];
  int h = lane >> 4;
  bool isbase = (lane & 15) == 0;
  int o0 = offs[n], dg = deg[n];
  int oend = o0 + dg;
  float mmax = -3.402823e38f;
  float ssum = 0.f;
  float acc  = 0.f;
  float easum = 0.f;   // meaningful in lanes 0..5
  int o = o0;
  for (; o+4 <= oend; o += 4){
    int2 c0=csr2[o], c1=csr2[o+1], c2=csr2[o+2], c3=csr2[o+3];
    float ev0=(lane<6)?eattr[(size_t)c0.x*6+lane]:0.f;
    float ev1=(lane<6)?eattr[(size_t)c1.x*6+lane]:0.f;
    float ev2=(lane<6)?eattr[(size_t)c2.x*6+lane]:0.f;
    float ev3=(lane<6)?eattr[(size_t)c3.x*6+lane]:0.f;
    float xv0=xl[(size_t)c0.y*64+lane];
    float xv1=xl[(size_t)c1.y*64+lane];
    float xv2=xl[(size_t)c2.y*64+lane];
    float xv3=xl[(size_t)c3.y*64+lane];
    easum += (ev0+ev1)+(ev2+ev3);
    EDGE_STEP(c0.x, ev0, xv0);
    EDGE_STEP(c1.x, ev1, xv1);
    EDGE_STEP(c2.x, ev2, xv2);
    EDGE_STEP(c3.x, ev3, xv3);
  }
  for (; o < oend; ++o){
    int2 c0=csr2[o];
    float ev0=(lane<6)?eattr[(size_t)c0.x*6+lane]:0.f;
    float xv0=xl[(size_t)c0.y*64+lane];
    easum += ev0;
    EDGE_STEP(c0.x, ev0, xv0);
  }
  // self-loop (edge id E+n): attr = mean of in-edge attrs, src = n
  {
    float ev = easum * (1.f/fmaxf((float)dg,1.f));
    float xv = xl[(size_t)n*64+lane];
    EDGE_STEP(E+n, ev, xv);
  }
  float sinv = 1.f/(ssum + 1e-16f);
  if (isbase){ mbuf[n*4+h]=mmax; sbuf[n*4+h]=sinv; }
  float outv = acc*sinv + bv;
  if (do_relu) outv = fmaxf(outv, 0.f);
  hout[(size_t)n*64+lane] = outv;
}

// ---------------- alpha finalize: edge-parallel, coalesced ----------------
__global__ void alpha_kernel(const int* __restrict__ ei,
                             const float* __restrict__ mbuf, const float* __restrict__ sbuf,
                             float* __restrict__ aout, int E, int N)
{
  int idx = blockIdx.x*256 + threadIdx.x;
  int tot = (E+N)*4;
  if (idx >= tot) return;
  int e = idx>>2, h = idx&3;
  int dst = (e<E)? ei[E+e] : (e-E);
  float raw = aout[idx];
  aout[idx] = __expf(raw - mbuf[dst*4+h]) * sbuf[dst*4+h];
}

// ---------------- GRU (n < T) + copy (T <= n < N), 8 nodes per wave ----------------
__global__ __launch_bounds__(256) void gru_kernel(
    const float* __restrict__ h2, const float* __restrict__ hid,
    const float* __restrict__ Wi, const float* __restrict__ bi,
    const float* __restrict__ Wh, const float* __restrict__ bh,
    const int* __restrict__ Tptr, float* __restrict__ nf, int N)
{
  int lane = threadIdx.x & 63;
  int T = *Tptr;
  int n0 = (blockIdx.x*4 + (threadIdx.x>>6))*8;
  if (n0 >= N) return;
  float hv[8];
  #pragma unroll
  for (int m=0;m<8;m++){ int n=n0+m; hv[m] = (n<N)? h2[(size_t)n*64+lane] : 0.f; }
  if (n0 >= T){
    #pragma unroll
    for (int m=0;m<8;m++){ int n=n0+m; if (n<N) nf[(size_t)n*64+lane]=hv[m]; }
    return;
  }
  float pv[8];
  #pragma unroll
  for (int m=0;m<8;m++){ int n=n0+m; pv[m] = (n<T)? hid[(size_t)n*64+lane] : 0.f; }
  float gr[8],gz[8],gn[8],hr[8],hz[8],hn[8];
  #pragma unroll
  for (int m=0;m<8;m++){ gr[m]=0.f;gz[m]=0.f;gn[m]=0.f;hr[m]=0.f;hz[m]=0.f;hn[m]=0.f; }
  for (int k=0;k<64;k++){
    float wir=Wi[k*192+lane], wiz=Wi[k*192+64+lane], win=Wi[k*192+128+lane];
    float whr=Wh[k*192+lane], whz=Wh[k*192+64+lane], whn=Wh[k*192+128+lane];
    #pragma unroll
    for (int m=0;m<8;m++){
      float a=__shfl(hv[m],k), b=__shfl(pv[m],k);
      gr[m]+=a*wir; gz[m]+=a*wiz; gn[m]+=a*win;
      hr[m]+=b*whr; hz[m]+=b*whz; hn[m]+=b*whn;
    }
  }
  float bir=bi[lane], biz=bi[64+lane], bin=bi[128+lane];
  float bhr=bh[lane], bhz=bh[64+lane], bhn=bh[128+lane];
  #pragma unroll
  for (int m=0;m<8;m++){
    int n=n0+m;
    if (n<T){
      float r  = sigmoidf_(gr[m]+bir + hr[m]+bhr);
      float z  = sigmoidf_(gz[m]+biz + hz[m]+bhz);
      float nn = tanhf(gn[m]+bin + r*(hn[m]+bhn));
      nf[(size_t)n*64+lane] = (1.f-z)*nn + z*pv[m];
    } else if (n<N){
      nf[(size_t)n*64+lane] = hv[m];
    }
  }
}

// ---------------- decoder ----------------
__global__ __launch_bounds__(256) void dec_kernel(
    const float* __restrict__ nf, const float* __restrict__ x, const float* __restrict__ pos,
    const float* __restrict__ W1, const float* __restrict__ b1,
    const float* __restrict__ W2, const float* __restrict__ b2,
    float* __restrict__ fout, int N)
{
  __shared__ float sW1[64*64];
  __shared__ float sW2[64*7];
  __shared__ float sb1[64];
  __shared__ float sb2[7];
  for (int i=threadIdx.x;i<64*64;i+=256) sW1[i]=W1[i];
  for (int i=threadIdx.x;i<64*7;i+=256) sW2[i]=W2[i];
  if (threadIdx.x<64) sb1[threadIdx.x]=b1[threadIdx.x];
  if (threadIdx.x<7)  sb2[threadIdx.x]=b2[threadIdx.x];
  __syncthreads();
  int lane = threadIdx.x & 63;
  int n0 = (blockIdx.x*4 + (threadIdx.x>>6))*4;
  if (n0>=N) return;
  float hv[4];
  #pragma unroll
  for (int m=0;m<4;m++){ int n=n0+m; hv[m]=(n<N)? nf[(size_t)n*64+lane] : 0.f; }
  float t[4];
  #pragma unroll
  for (int m=0;m<4;m++) t[m]=sb1[lane];
  for (int k=0;k<64;k++){
    float w=sW1[k*64+lane];
    #pragma unroll
    for (int m=0;m<4;m++) t[m] += __shfl(hv[m],k)*w;
  }
  #pragma unroll
  for (int m=0;m<4;m++) t[m]=fmaxf(t[m],0.f);
  #pragma unroll
  for (int c=0;c<7;c++){
    float w = sW2[lane*7+c];
    float p0=t[0]*w, p1=t[1]*w, p2=t[2]*w, p3=t[3]*w;
    #pragma unroll
    for (int d=1;d<64;d<<=1){
      p0+=__shfl_xor(p0,d); p1+=__shfl_xor(p1,d); p2+=__shfl_xor(p2,d); p3+=__shfl_xor(p3,d);
    }
    if (lane==c){
      float b = sb2[c];
      float pm[4]={p0,p1,p2,p3};
      #pragma unroll
      for (int m=0;m<4;m++){
        int n=n0+m;
        if (n<N){
          float val = pm[m]+b;
          if (c<3)      val += pos[(size_t)n*3+c];
          else if (c<6) val += x[(size_t)n*7+(c-3)];
          fout[(size_t)n*7+c] = val;
        }
      }
    }
  }
}

extern "C" void kernel_launch(void* const* d_in, const int* in_sizes, int n_in,
                              void* d_out, int out_size, void* d_ws, size_t ws_size,
                              hipStream_t stream)
{
  const float* x     = (const float*)d_in[0];
  const float* pos   = (const float*)d_in[1];
  const int*   ntype = (const int*)d_in[2];
  const int*   eidx  = (const int*)d_in[3];
  const float* eattr = (const float*)d_in[4];
  const int*   Tptr  = (const int*)d_in[5];
  const float* hid   = (const float*)d_in[6];
  const float* temb  = (const float*)d_in[7];
  const float* encW1 = (const float*)d_in[8];
  const float* encb1 = (const float*)d_in[9];
  const float* encW2 = (const float*)d_in[10];
  const float* encb2 = (const float*)d_in[11];
  const float* gruWi = (const float*)d_in[12];
  const float* grubi = (const float*)d_in[13];
  const float* gruWh = (const float*)d_in[14];
  const float* grubh = (const float*)d_in[15];
  const float* decW1 = (const float*)d_in[16];
  const float* decb1 = (const float*)d_in[17];
  const float* decW2 = (const float*)d_in[18];
  const float* decb2 = (const float*)d_in[19];
  const float* gWl[2]  = {(const float*)d_in[20], (const float*)d_in[27]};
  const float* gbl[2]  = {(const float*)d_in[21], (const float*)d_in[28]};
  const float* gWr[2]  = {(const float*)d_in[22], (const float*)d_in[29]};
  const float* gbr[2]  = {(const float*)d_in[23], (const float*)d_in[30]};
  const float* gWe[2]  = {(const float*)d_in[24], (const float*)d_in[31]};
  const float* gatt[2] = {(const float*)d_in[25], (const float*)d_in[32]};
  const float* gbias[2]= {(const float*)d_in[26], (const float*)d_in[33]};

  int N  = in_sizes[0] / 7;
  int E  = in_sizes[3] / 2;
  int Ea = E + N;
  int NB = (N + SCHUNK - 1) / SCHUNK;

  char* w = (char*)d_ws;
  float* A      = (float*)w; w += (size_t)N*64*sizeof(float);
  float* B      = (float*)w; w += (size_t)N*64*sizeof(float);
  float* C      = (float*)w; w += (size_t)N*64*sizeof(float);
  int*   deg    = (int*)w;   w += (size_t)N*sizeof(int);
  int*   offs   = (int*)w;   w += (size_t)N*sizeof(int);
  int*   cursor = (int*)w;   w += (size_t)N*sizeof(int);
  int*   bsum   = (int*)w;   w += (size_t)NB*sizeof(int);
  int*   bscan  = (int*)w;   w += (size_t)NB*sizeof(int);
  float* mbuf   = (float*)w; w += (size_t)N*4*sizeof(float);
  float* sbuf   = (float*)w; w += (size_t)N*4*sizeof(float);
  int2*  csr2   = (int2*)w;  w += (size_t)Ea*sizeof(int2);

  float* out_final = (float*)d_out;
  float* out_nf    = out_final + (size_t)N*7;
  float* out_a1    = out_nf + (size_t)N*64;
  float* out_a2    = out_a1 + (size_t)Ea*4;

  hipMemsetAsync(deg,    0, (size_t)N*sizeof(int), stream);
  hipMemsetAsync(cursor, 0, (size_t)N*sizeof(int), stream);

  enc_kernel<<<(N+15)/16, 256, 0, stream>>>(x,pos,ntype,temb,encW1,encb1,encW2,encb2,A,N);
  deg_kernel<<<(E+255)/256, 256, 0, stream>>>(eidx, deg, E);
  scan_reduce<<<NB, 256, 0, stream>>>(deg, bsum, N);
  scan_bsums<<<1, 1024, 0, stream>>>(bsum, bscan, NB);
  scan_final<<<NB, 256, 0, stream>>>(deg, bscan, offs, N);
  fill_kernel<<<(Ea+255)/256, 256, 0, stream>>>(eidx, offs, deg, cursor, csr2, E, N);

  // layer 1: h(A) -> xl(A, in-place), xr(C); out h1 -> B (relu)
  xfrm_kernel<<<(N+15)/16, 256, 0, stream>>>(A, gWl[0], gbl[0], gWr[0], gbr[0], A, C, N);
  gat_kernel<<<(N+3)/4, 256, 0, stream>>>(csr2, offs, deg, eattr, A, C,
      gWe[0], gatt[0], gbias[0], out_a1, mbuf, sbuf, B, E, N, 1);
  alpha_kernel<<<((size_t)Ea*4+255)/256, 256, 0, stream>>>(eidx, mbuf, sbuf, out_a1, E, N);

  // layer 2: h1(B) -> xl(B, in-place), xr(C); out h2 -> A (no relu)
  xfrm_kernel<<<(N+15)/16, 256, 0, stream>>>(B, gWl[1], gbl[1], gWr[1], gbr[1], B, C, N);
  gat_kernel<<<(N+3)/4, 256, 0, stream>>>(csr2, offs, deg, eattr, B, C,
      gWe[1], gatt[1], gbias[1], out_a2, mbuf, sbuf, A, E, N, 0);
  alpha_kernel<<<((size_t)Ea*4+255)/256, 256, 0, stream>>>(eidx, mbuf, sbuf, out_a2, E, N);

  gru_kernel<<<(N+31)/32, 256, 0, stream>>>(A, hid, gruWi, grubi, gruWh, grubh, Tptr, out_nf, N);
  dec_kernel<<<(N+15)/16, 256, 0, stream>>>(out_nf, x, pos, decW1, decb1, decW2, decb2, out_final, N);
}

// Round 4
// 826.769 us; speedup vs baseline: 2.5912x; 1.2419x over previous
//
#include <hip/hip_runtime.h>

#define NEG 0.2f
#define SCHUNK 1024

__device__ __forceinline__ float sigmoidf_(float v){ return 1.f/(1.f+__expf(-v)); }
__device__ __forceinline__ int rfl_(int v){ return __builtin_amdgcn_readfirstlane(v); }

// ---------------- encoder: h = relu([x,pos,temb[nt]] @ W1 + b1) @ W2 + b2 ----------------
__global__ __launch_bounds__(256) void enc_kernel(
    const float* __restrict__ x, const float* __restrict__ pos,
    const int* __restrict__ ntype, const float* __restrict__ temb,
    const float* __restrict__ W1, const float* __restrict__ b1,
    const float* __restrict__ W2, const float* __restrict__ b2,
    float* __restrict__ hout, int N)
{
  __shared__ float sW1[18*64];
  __shared__ float sW2[64*64];
  __shared__ float sb1[64], sb2[64];
  __shared__ float tT[4][256];
  for (int i=threadIdx.x; i<18*64; i+=256) sW1[i]=W1[i];
  for (int i=threadIdx.x; i<64*64; i+=256) sW2[i]=W2[i];
  if (threadIdx.x<64){ sb1[threadIdx.x]=b1[threadIdx.x]; sb2[threadIdx.x]=b2[threadIdx.x]; }
  __syncthreads();
  int lane = threadIdx.x & 63;
  int wid  = threadIdx.x >> 6;
  int n0 = (blockIdx.x*4 + wid)*4;
  if (n0 >= N) return;
  float f[4];
  #pragma unroll
  for (int m=0;m<4;m++){
    int n=n0+m; f[m]=0.f;
    if (n<N){
      if (lane<7)       f[m]=x[(size_t)n*7+lane];
      else if (lane<10) f[m]=pos[(size_t)n*3+lane-7];
      else if (lane<18) f[m]=temb[ntype[n]*8+lane-10];
    }
  }
  float t[4];
  #pragma unroll
  for (int m=0;m<4;m++) t[m]=sb1[lane];
  for (int k=0;k<18;k++){
    float w=sW1[k*64+lane];
    #pragma unroll
    for (int m=0;m<4;m++) t[m] += __shfl(f[m],k)*w;
  }
  #pragma unroll
  for (int m=0;m<4;m++) t[m]=fmaxf(t[m],0.f);
  // transpose-stage t for stage 2 (per-wave private tile)
  *(float4*)&tT[wid][lane*4] = make_float4(t[0],t[1],t[2],t[3]);
  float o[4];
  #pragma unroll
  for (int m=0;m<4;m++) o[m]=sb2[lane];
  for (int k=0;k<64;k++){
    float4 tb = *(const float4*)&tT[wid][k*4];
    float w=sW2[k*64+lane];
    o[0]+=tb.x*w; o[1]+=tb.y*w; o[2]+=tb.z*w; o[3]+=tb.w*w;
  }
  #pragma unroll
  for (int m=0;m<4;m++){ int n=n0+m; if (n<N) hout[(size_t)n*64+lane]=o[m]; }
}

// ---------------- degree ----------------
__global__ void deg_kernel(const int* __restrict__ ei, int* __restrict__ deg, int E)
{
  int e = blockIdx.x*256 + threadIdx.x;
  if (e>=E) return;
  atomicAdd(deg + ei[E+e], 1);
}

// ---------------- 3-phase multi-block exclusive scan of (deg+1) -> offs[N] ----------------
__global__ __launch_bounds__(256) void scan_reduce(const int* __restrict__ deg, int* __restrict__ bsum, int N)
{
  int base = blockIdx.x*SCHUNK + threadIdx.x*4;
  int s=0;
  #pragma unroll
  for (int j=0;j<4;j++){ int i=base+j; s += (i<N)? deg[i]+1 : 0; }
  #pragma unroll
  for (int d=1;d<64;d<<=1) s += __shfl_xor(s,d);
  __shared__ int ws[4];
  if ((threadIdx.x&63)==0) ws[threadIdx.x>>6]=s;
  __syncthreads();
  if (threadIdx.x==0) bsum[blockIdx.x]=ws[0]+ws[1]+ws[2]+ws[3];
}

__global__ __launch_bounds__(1024) void scan_bsums(const int* __restrict__ bsum, int* __restrict__ bscan, int NB)
{
  int tid = threadIdx.x;
  int lane = tid&63, w = tid>>6;
  int v = (tid<NB)? bsum[tid] : 0;
  int inc = v;
  #pragma unroll
  for (int d=1;d<64;d<<=1){ int t=__shfl_up(inc,d); if (lane>=d) inc+=t; }
  __shared__ int wsum[16], woff[16];
  if (lane==63) wsum[w]=inc;
  __syncthreads();
  if (w==0){
    int s=(lane<16)?wsum[lane]:0; int sc=s;
    #pragma unroll
    for (int d=1;d<16;d<<=1){ int t=__shfl_up(sc,d); if (lane>=d) sc+=t; }
    if (lane<16) woff[lane]=sc-s;
  }
  __syncthreads();
  int excl = woff[w] + inc - v;
  if (tid<NB) bscan[tid]=excl;
}

__global__ __launch_bounds__(256) void scan_final(const int* __restrict__ deg, const int* __restrict__ bscan,
                                                  int* __restrict__ offs, int N)
{
  int lane = threadIdx.x&63, w = threadIdx.x>>6;
  int base = blockIdx.x*SCHUNK + threadIdx.x*4;
  int v[4]; int s=0;
  #pragma unroll
  for (int j=0;j<4;j++){ int i=base+j; v[j]=(i<N)?deg[i]+1:0; s+=v[j]; }
  int inc=s;
  #pragma unroll
  for (int d=1;d<64;d<<=1){ int t=__shfl_up(inc,d); if (lane>=d) inc+=t; }
  __shared__ int wsum[4], woff[4];
  if (lane==63) wsum[w]=inc;
  __syncthreads();
  if (threadIdx.x==0){ woff[0]=0; woff[1]=wsum[0]; woff[2]=wsum[0]+wsum[1]; woff[3]=wsum[0]+wsum[1]+wsum[2]; }
  __syncthreads();
  int excl = bscan[blockIdx.x] + woff[w] + (inc - s);
  #pragma unroll
  for (int j=0;j<4;j++){ int i=base+j; if (i<N) offs[i]=excl; excl+=v[j]; }
}

// ---------------- CSR fill: csr2[slot] = {edge_id, src}; self-loop pinned to LAST slot ----------------
__global__ void fill_kernel(const int* __restrict__ ei, const int* __restrict__ offs,
                            const int* __restrict__ deg, int* __restrict__ cursor,
                            int2* __restrict__ csr2, int E, int N)
{
  int e = blockIdx.x*256 + threadIdx.x;
  int Ea = E + N;
  if (e >= Ea) return;
  if (e < E){
    int dst = ei[E + e];
    int p = atomicAdd(cursor + dst, 1);
    csr2[offs[dst] + p] = make_int2(e, ei[e]);
  } else {
    int n = e - E;
    csr2[offs[n] + deg[n]] = make_int2(e, n);
  }
}

// ---------------- xl = h@Wl+bl, xr = h@Wr+br (in-place safe for hin==xlo) ----------------
__global__ __launch_bounds__(256) void xfrm_kernel(
    const float* hin,
    const float* __restrict__ Wl, const float* __restrict__ bl,
    const float* __restrict__ Wr, const float* __restrict__ br,
    float* xlo, float* __restrict__ xro, int N)
{
  __shared__ float sWl[4096], sWr[4096], sbl[64], sbr[64];
  __shared__ float hT[4][256];
  for (int i=threadIdx.x;i<4096;i+=256){ sWl[i]=Wl[i]; sWr[i]=Wr[i]; }
  if (threadIdx.x<64){ sbl[threadIdx.x]=bl[threadIdx.x]; sbr[threadIdx.x]=br[threadIdx.x]; }
  __syncthreads();
  int lane=threadIdx.x&63;
  int wid=threadIdx.x>>6;
  int n0=(blockIdx.x*4+wid)*4;
  if (n0>=N) return;
  float hv[4];
  #pragma unroll
  for (int m=0;m<4;m++){ int n=n0+m; hv[m]=(n<N)? hin[(size_t)n*64+lane]:0.f; }
  // per-wave transpose tile: hT[wid][k*4+m] = h[node m][k]
  *(float4*)&hT[wid][lane*4] = make_float4(hv[0],hv[1],hv[2],hv[3]);
  float al[4], ar[4];
  #pragma unroll
  for (int m=0;m<4;m++){ al[m]=sbl[lane]; ar[m]=sbr[lane]; }
  for (int k=0;k<64;k++){
    float4 hb = *(const float4*)&hT[wid][k*4];   // uniform addr -> broadcast
    float wl=sWl[k*64+lane], wr=sWr[k*64+lane];
    al[0]+=hb.x*wl; al[1]+=hb.y*wl; al[2]+=hb.z*wl; al[3]+=hb.w*wl;
    ar[0]+=hb.x*wr; ar[1]+=hb.y*wr; ar[2]+=hb.z*wr; ar[3]+=hb.w*wr;
  }
  #pragma unroll
  for (int m=0;m<4;m++){
    int n=n0+m;
    if (n<N){ xlo[(size_t)n*64+lane]=al[m]; xro[(size_t)n*64+lane]=ar[m]; }
  }
}

// ---------------- fused GATv2 layer: wave per dst node, scalarized + defer-max ----------------
// All per-edge metadata (edge id, src, 6 eattr floats) is wave-uniform -> SGPRs.
// EADD = precomputed ea@We contribution (per-lane), XV = gathered xl[src].
#define EDGE_STEP(EIDX, EADD, XV) do {                                       \
    float s_ = (XV) + xrv + (EADD);                                          \
    s_ = fmaxf(s_, NEG*s_);                                                  \
    float p_ = s_*attv;                                                      \
    p_ += __shfl_xor(p_,1); p_ += __shfl_xor(p_,2);                          \
    p_ += __shfl_xor(p_,4); p_ += __shfl_xor(p_,8);                          \
    if (isbase) aout[(size_t)(EIDX)*4+h] = p_;                               \
    if (__all(p_ <= mmax)) {                                                 \
      float w_ = __expf(p_ - mmax);                                          \
      ssum += w_; acc += w_*(XV);                                            \
    } else {                                                                 \
      float mn_ = fmaxf(mmax, p_);                                           \
      float sc_ = __expf(mmax - mn_);                                        \
      float w_  = __expf(p_ - mn_);                                          \
      ssum = ssum*sc_ + w_;                                                  \
      acc  = acc*sc_ + w_*(XV);                                              \
      mmax = mn_;                                                            \
    }                                                                        \
  } while(0)

#define EDGE_PRE(J) \
    int e##J = rfl_(c##J.x), s##J = rfl_(c##J.y); \
    const float2* q##J = (const float2*)(eattr + (size_t)e##J*6); \
    float2 A##J=q##J[0], B##J=q##J[1], C##J=q##J[2]; \
    float xv##J = xl[(size_t)s##J*64+lane];

#define EDGE_BODY(J) \
    ea01.x+=A##J.x; ea01.y+=A##J.y; ea23.x+=B##J.x; ea23.y+=B##J.y; ea45.x+=C##J.x; ea45.y+=C##J.y; \
    float d##J = A##J.x*we0 + A##J.y*we1 + B##J.x*we2 + B##J.y*we3 + C##J.x*we4 + C##J.y*we5; \
    EDGE_STEP(e##J, d##J, xv##J);

__global__ __launch_bounds__(256) void gat_kernel(
    const int2* __restrict__ csr2, const int* __restrict__ offs, const int* __restrict__ deg,
    const float* __restrict__ eattr,
    const float* __restrict__ xl, const float* __restrict__ xr,
    const float* __restrict__ We, const float* __restrict__ att,
    const float* __restrict__ bias,
    float* __restrict__ aout, float2* __restrict__ msbuf,
    float* __restrict__ hout,
    int E, int N, int do_relu)
{
  int lane = threadIdx.x & 63;
  int n = blockIdx.x*4 + (threadIdx.x>>6);
  if (n >= N) return;
  float we0=We[lane], we1=We[64+lane], we2=We[128+lane],
        we3=We[192+lane], we4=We[256+lane], we5=We[320+lane];
  float attv = att[lane];
  float bv = bias[lane];
  float xrv = xr[(size_t)n*64+lane];
  int h = lane >> 4;
  bool isbase = (lane & 15) == 0;
  int o0 = rfl_(offs[n]);
  int dg = rfl_(deg[n]);
  int oend = o0 + dg;
  float mmax = -3.402823e38f, ssum=0.f, acc=0.f;
  float2 ea01=make_float2(0.f,0.f), ea23=make_float2(0.f,0.f), ea45=make_float2(0.f,0.f);
  int o = o0;
  for (; o+4 <= oend; o += 4){
    int2 c0=csr2[o], c1=csr2[o+1], c2=csr2[o+2], c3=csr2[o+3];
    EDGE_PRE(0); EDGE_PRE(1); EDGE_PRE(2); EDGE_PRE(3);
    EDGE_BODY(0); EDGE_BODY(1); EDGE_BODY(2); EDGE_BODY(3);
  }
  for (; o < oend; ++o){
    int2 c0=csr2[o];
    EDGE_PRE(0);
    EDGE_BODY(0);
  }
  // self-loop (edge id E+n): attr = mean of in-edge attrs, src = n
  {
    float inv = 1.f/fmaxf((float)dg,1.f);
    float dS = (ea01.x*inv)*we0 + (ea01.y*inv)*we1 + (ea23.x*inv)*we2
             + (ea23.y*inv)*we3 + (ea45.x*inv)*we4 + (ea45.y*inv)*we5;
    float xvS = xl[(size_t)n*64+lane];
    EDGE_STEP(E+n, dS, xvS);
  }
  float sinv = 1.f/(ssum + 1e-16f);
  if (isbase) msbuf[(size_t)n*4+h] = make_float2(mmax, sinv);
  float outv = acc*sinv + bv;
  if (do_relu) outv = fmaxf(outv, 0.f);
  hout[(size_t)n*64+lane] = outv;
}

// ---------------- alpha finalize: one thread per edge, float4 I/O ----------------
__global__ void alpha_kernel(const int* __restrict__ ei, const float2* __restrict__ msbuf,
                             float4* __restrict__ aout4, int E, int N)
{
  int e = blockIdx.x*256 + threadIdx.x;
  if (e >= E+N) return;
  int dst = (e<E)? ei[E+e] : (e-E);
  float4 r = aout4[e];
  const float2* mp = msbuf + (size_t)dst*4;
  float2 m0=mp[0], m1=mp[1], m2=mp[2], m3=mp[3];
  float4 o;
  o.x = __expf(r.x - m0.x)*m0.y;
  o.y = __expf(r.y - m1.x)*m1.y;
  o.z = __expf(r.z - m2.x)*m2.y;
  o.w = __expf(r.w - m3.x)*m3.y;
  aout4[e] = o;
}

// ---------------- fused GRU + decoder: 4 nodes per wave ----------------
__global__ __launch_bounds__(256) void grudec_kernel(
    const float* __restrict__ h2, const float* __restrict__ hid,
    const float* __restrict__ Wi, const float* __restrict__ bi,
    const float* __restrict__ Wh, const float* __restrict__ bh,
    const int* __restrict__ Tptr,
    const float* __restrict__ W1, const float* __restrict__ b1,
    const float* __restrict__ W2, const float* __restrict__ b2,
    const float* __restrict__ x, const float* __restrict__ pos,
    float* __restrict__ nf, float* __restrict__ fout, int N)
{
  __shared__ float sW1[4096];
  __shared__ float sW2[448];
  __shared__ float sb1[64];
  __shared__ float sb2[7];
  __shared__ float tT[4][256];
  __shared__ float pT[4][256];
  for (int i=threadIdx.x;i<4096;i+=256) sW1[i]=W1[i];
  for (int i=threadIdx.x;i<448;i+=256) sW2[i]=W2[i];
  if (threadIdx.x<64) sb1[threadIdx.x]=b1[threadIdx.x];
  if (threadIdx.x<7)  sb2[threadIdx.x]=b2[threadIdx.x];
  __syncthreads();
  int lane = threadIdx.x & 63;
  int wid  = threadIdx.x >> 6;
  int n0 = (blockIdx.x*4 + wid)*4;
  int T = *Tptr;
  float hv[4], nfv[4];
  #pragma unroll
  for (int m=0;m<4;m++){ int n=n0+m; hv[m] = (n<N)? h2[(size_t)n*64+lane] : 0.f; }
  if (n0 < T){
    float pv[4];
    #pragma unroll
    for (int m=0;m<4;m++){ int n=n0+m; pv[m] = (n<T)? hid[(size_t)n*64+lane] : 0.f; }
    *(float4*)&tT[wid][lane*4] = make_float4(hv[0],hv[1],hv[2],hv[3]);
    *(float4*)&pT[wid][lane*4] = make_float4(pv[0],pv[1],pv[2],pv[3]);
    float gr[4],gz[4],gn[4],hr[4],hz[4],hn[4];
    #pragma unroll
    for (int m=0;m<4;m++){ gr[m]=0.f;gz[m]=0.f;gn[m]=0.f;hr[m]=0.f;hz[m]=0.f;hn[m]=0.f; }
    for (int k=0;k<64;k++){
      float4 hb = *(const float4*)&tT[wid][k*4];
      float4 pb = *(const float4*)&pT[wid][k*4];
      float wir=Wi[k*192+lane], wiz=Wi[k*192+64+lane], win=Wi[k*192+128+lane];
      float whr=Wh[k*192+lane], whz=Wh[k*192+64+lane], whn=Wh[k*192+128+lane];
      gr[0]+=hb.x*wir; gr[1]+=hb.y*wir; gr[2]+=hb.z*wir; gr[3]+=hb.w*wir;
      gz[0]+=hb.x*wiz; gz[1]+=hb.y*wiz; gz[2]+=hb.z*wiz; gz[3]+=hb.w*wiz;
      gn[0]+=hb.x*win; gn[1]+=hb.y*win; gn[2]+=hb.z*win; gn[3]+=hb.w*win;
      hr[0]+=pb.x*whr; hr[1]+=pb.y*whr; hr[2]+=pb.z*whr; hr[3]+=pb.w*whr;
      hz[0]+=pb.x*whz; hz[1]+=pb.y*whz; hz[2]+=pb.z*whz; hz[3]+=pb.w*whz;
      hn[0]+=pb.x*whn; hn[1]+=pb.y*whn; hn[2]+=pb.z*whn; hn[3]+=pb.w*whn;
    }
    float bir=bi[lane], biz=bi[64+lane], bin=bi[128+lane];
    float bhr=bh[lane], bhz=bh[64+lane], bhn=bh[128+lane];
    #pragma unroll
    for (int m=0;m<4;m++){
      int n=n0+m;
      if (n<T){
        float r  = sigmoidf_(gr[m]+bir + hr[m]+bhr);
        float z  = sigmoidf_(gz[m]+biz + hz[m]+bhz);
        float nn = tanhf(gn[m]+bin + r*(hn[m]+bhn));
        nfv[m] = (1.f-z)*nn + z*pv[m];
      } else {
        nfv[m] = hv[m];
      }
    }
  } else {
    #pragma unroll
    for (int m=0;m<4;m++) nfv[m] = hv[m];
  }
  #pragma unroll
  for (int m=0;m<4;m++){ int n=n0+m; if (n<N) nf[(size_t)n*64+lane]=nfv[m]; }
  // ---- decoder stage 1: t = relu(nf@W1 + b1) ----
  *(float4*)&tT[wid][lane*4] = make_float4(nfv[0],nfv[1],nfv[2],nfv[3]);
  float t[4];
  #pragma unroll
  for (int m=0;m<4;m++) t[m]=sb1[lane];
  for (int k=0;k<64;k++){
    float4 nb = *(const float4*)&tT[wid][k*4];
    float w = sW1[k*64+lane];
    t[0]+=nb.x*w; t[1]+=nb.y*w; t[2]+=nb.z*w; t[3]+=nb.w*w;
  }
  #pragma unroll
  for (int m=0;m<4;m++) t[m]=fmaxf(t[m],0.f);
  // ---- decoder stage 2: out = t@W2 + b2 (+ residuals) ----
  #pragma unroll
  for (int c=0;c<7;c++){
    float w = sW2[lane*7+c];
    float p0=t[0]*w, p1=t[1]*w, p2=t[2]*w, p3=t[3]*w;
    #pragma unroll
    for (int d=1;d<64;d<<=1){
      p0+=__shfl_xor(p0,d); p1+=__shfl_xor(p1,d); p2+=__shfl_xor(p2,d); p3+=__shfl_xor(p3,d);
    }
    if (lane==c){
      float b = sb2[c];
      float pm[4]={p0,p1,p2,p3};
      #pragma unroll
      for (int m=0;m<4;m++){
        int n=n0+m;
        if (n<N){
          float val = pm[m]+b;
          if (c<3)      val += pos[(size_t)n*3+c];
          else if (c<6) val += x[(size_t)n*7+(c-3)];
          fout[(size_t)n*7+c] = val;
        }
      }
    }
  }
}

extern "C" void kernel_launch(void* const* d_in, const int* in_sizes, int n_in,
                              void* d_out, int out_size, void* d_ws, size_t ws_size,
                              hipStream_t stream)
{
  const float* x     = (const float*)d_in[0];
  const float* pos   = (const float*)d_in[1];
  const int*   ntype = (const int*)d_in[2];
  const int*   eidx  = (const int*)d_in[3];
  const float* eattr = (const float*)d_in[4];
  const int*   Tptr  = (const int*)d_in[5];
  const float* hid   = (const float*)d_in[6];
  const float* temb  = (const float*)d_in[7];
  const float* encW1 = (const float*)d_in[8];
  const float* encb1 = (const float*)d_in[9];
  const float* encW2 = (const float*)d_in[10];
  const float* encb2 = (const float*)d_in[11];
  const float* gruWi = (const float*)d_in[12];
  const float* grubi = (const float*)d_in[13];
  const float* gruWh = (const float*)d_in[14];
  const float* grubh = (const float*)d_in[15];
  const float* decW1 = (const float*)d_in[16];
  const float* decb1 = (const float*)d_in[17];
  const float* decW2 = (const float*)d_in[18];
  const float* decb2 = (const float*)d_in[19];
  const float* gWl[2]  = {(const float*)d_in[20], (const float*)d_in[27]};
  const float* gbl[2]  = {(const float*)d_in[21], (const float*)d_in[28]};
  const float* gWr[2]  = {(const float*)d_in[22], (const float*)d_in[29]};
  const float* gbr[2]  = {(const float*)d_in[23], (const float*)d_in[30]};
  const float* gWe[2]  = {(const float*)d_in[24], (const float*)d_in[31]};
  const float* gatt[2] = {(const float*)d_in[25], (const float*)d_in[32]};
  const float* gbias[2]= {(const float*)d_in[26], (const float*)d_in[33]};

  int N  = in_sizes[0] / 7;
  int E  = in_sizes[3] / 2;
  int Ea = E + N;
  int NB = (N + SCHUNK - 1) / SCHUNK;

  char* w = (char*)d_ws;
  float* A      = (float*)w; w += (size_t)N*64*sizeof(float);
  float* B      = (float*)w; w += (size_t)N*64*sizeof(float);
  float* C      = (float*)w; w += (size_t)N*64*sizeof(float);
  int*   deg    = (int*)w;   w += (size_t)N*sizeof(int);
  int*   offs   = (int*)w;   w += (size_t)N*sizeof(int);
  int*   cursor = (int*)w;   w += (size_t)N*sizeof(int);
  int*   bsum   = (int*)w;   w += (size_t)NB*sizeof(int);
  int*   bscan  = (int*)w;   w += (size_t)NB*sizeof(int);
  float2* msbuf = (float2*)w; w += (size_t)N*4*sizeof(float2);
  int2*  csr2   = (int2*)w;  w += (size_t)Ea*sizeof(int2);

  float* out_final = (float*)d_out;
  float* out_nf    = out_final + (size_t)N*7;
  float* out_a1    = out_nf + (size_t)N*64;
  float* out_a2    = out_a1 + (size_t)Ea*4;

  hipMemsetAsync(deg,    0, (size_t)N*sizeof(int), stream);
  hipMemsetAsync(cursor, 0, (size_t)N*sizeof(int), stream);

  enc_kernel<<<(N+15)/16, 256, 0, stream>>>(x,pos,ntype,temb,encW1,encb1,encW2,encb2,A,N);
  deg_kernel<<<(E+255)/256, 256, 0, stream>>>(eidx, deg, E);
  scan_reduce<<<NB, 256, 0, stream>>>(deg, bsum, N);
  scan_bsums<<<1, 1024, 0, stream>>>(bsum, bscan, NB);
  scan_final<<<NB, 256, 0, stream>>>(deg, bscan, offs, N);
  fill_kernel<<<(Ea+255)/256, 256, 0, stream>>>(eidx, offs, deg, cursor, csr2, E, N);

  // layer 1: h(A) -> xl(A, in-place), xr(C); out h1 -> B (relu)
  xfrm_kernel<<<(N+15)/16, 256, 0, stream>>>(A, gWl[0], gbl[0], gWr[0], gbr[0], A, C, N);
  gat_kernel<<<(N+3)/4, 256, 0, stream>>>(csr2, offs, deg, eattr, A, C,
      gWe[0], gatt[0], gbias[0], out_a1, msbuf, B, E, N, 1);
  alpha_kernel<<<(Ea+255)/256, 256, 0, stream>>>(eidx, msbuf, (float4*)out_a1, E, N);

  // layer 2: h1(B) -> xl(B, in-place), xr(C); out h2 -> A (no relu)
  xfrm_kernel<<<(N+15)/16, 256, 0, stream>>>(B, gWl[1], gbl[1], gWr[1], gbr[1], B, C, N);
  gat_kernel<<<(N+3)/4, 256, 0, stream>>>(csr2, offs, deg, eattr, B, C,
      gWe[1], gatt[1], gbias[1], out_a2, msbuf, A, E, N, 0);
  alpha_kernel<<<(Ea+255)/256, 256, 0, stream>>>(eidx, msbuf, (float4*)out_a2, E, N);

  grudec_kernel<<<(N+15)/16, 256, 0, stream>>>(A, hid, gruWi, grubi, gruWh, grubh, Tptr,
      decW1, decb1, decW2, decb2, x, pos, out_nf, out_final, N);
}